// Round 1
// 481.266 us; speedup vs baseline: 1.3182x; 1.3182x over previous
//
#include <hip/hip_runtime.h>
#include <hip/hip_bf16.h>

// S4D: B=8, L=4096, H=1024, N=32 complex modes. f32 in / f32 out.
// R5: register-pressure fix. Previous round's VGPR=68 (< 96 floats needed) meant the
// compiler re-loaded gr/gi from L2 every inner iteration (~30 TB/s of L2 traffic,
// at the L2 ceiling). scan_out: __launch_bounds__(256,4) -> 128-VGPR budget, all
// mode constants resident; paired-j epilogue (half 0 emits gelu for j, half 1 for
// j+1) so the erf polynomial runs unmasked once per 2 steps. scan_local: 4-way mode
// split (8 modes/lane, ~48 VGPR) + __launch_bounds__(256,8) -> 8 waves/SIMD, and
// prefetch distance 4 for the HBM-cold u stream. All hot-loop addressing is 32-bit
// (SGPR base + voffset); prefetch wrap via &(Lc-1) (loads stay in-chunk, unused).

#define B_ 8
#define L_ 4096
#define H_ 1024
#define N_ 32
#define NH_ 16  // modes per lane in scan_out (N_/2)
#define NQ_ 8   // modes per lane in scan_local (N_/4)

// ---------------- kernel A: per-(h,n) mode constants ----------------
// modes[n*H+h] = (w_r, w_i, g_r, g_i); w = exp(dt*A); g = (2 Re C', -2 Im C');
// C' = (C_r + i C_i)*(w-1)/A.  wLc[n*H+h] = w^(Lc).
__global__ void modes_kernel(const float* __restrict__ log_dt,
                             const float* __restrict__ A_real,
                             const float* __restrict__ A_imag,
                             const float* __restrict__ C_real,
                             const float* __restrict__ C_imag,
                             float4* __restrict__ modes,
                             float2* __restrict__ wLc,
                             int log2Lc) {
    int t = blockIdx.x * blockDim.x + threadIdx.x;
    if (t >= H_ * N_) return;
    int h = t / N_, n = t % N_;
    float dt = expf(log_dt[h]);
    float ar = -expf(A_real[t]);
    float ai = A_imag[t];
    float cr = C_real[t];
    float ci = C_imag[t];
    float dr = ar * dt, di = ai * dt;
    float e = expf(dr);
    float sn, cs;
    sincosf(di, &sn, &cs);
    float wr = e * cs, wi = e * sn;
    float inv = 1.0f / (ar * ar + ai * ai);
    float nr = wr - 1.0f, ni = wi;
    float qr = (nr * ar + ni * ai) * inv;
    float qi = (ni * ar - nr * ai) * inv;
    float gr = 2.0f * (cr * qr - ci * qi);
    float gi = -2.0f * (cr * qi + ci * qr);
    modes[n * H_ + h] = make_float4(wr, wi, gr, gi);
    float pr = wr, pi2 = wi;
    for (int i = 0; i < log2Lc; ++i) {
        float t2r = pr * pr - pi2 * pi2;
        float t2i = 2.0f * pr * pi2;
        pr = t2r; pi2 = t2i;
    }
    wLc[n * H_ + h] = make_float2(pr, pi2);
}

// ---------------- kernel B: local scan per chunk (zero entry state) ----------------
// Wave w: (b,c) = w>>6, h-tile = (w&63)*16. Lane: q = lane>>4 (mode quarter,
// 8 modes), k = lane&15 (h within tile). ~48 VGPR -> 8 waves/SIMD.
template <int C_>
__global__ __launch_bounds__(256, 8) void scan_local(const float* __restrict__ u,
                                                     const float4* __restrict__ modes,
                                                     float2* __restrict__ states) {
    constexpr int Lc = L_ / C_;
    int t = blockIdx.x * blockDim.x + threadIdx.x;
    int lane = t & 63;
    int w = t >> 6;
    int q = lane >> 4;
    int k = lane & 15;
    int h = (w & 63) * 16 + k;
    int bc = w >> 6;
    int c = bc % C_;
    int b = bc / C_;
    int nb = q * NQ_;
    float wr[NQ_], wi[NQ_], sr[NQ_], si[NQ_];
#pragma unroll
    for (int n = 0; n < NQ_; ++n) {
        float4 m = modes[(nb + n) * H_ + h];
        wr[n] = m.x; wi[n] = m.y; sr[n] = 0.0f; si[n] = 0.0f;
    }
    unsigned idx = ((unsigned)b * L_ + (unsigned)c * Lc) * H_ + (unsigned)h;
    float pre[4];
#pragma unroll
    for (int s = 0; s < 4; ++s) pre[s] = u[idx + (unsigned)(s * H_)];
    for (int j = 0; j < Lc; j += 4) {
#pragma unroll
        for (int s = 0; s < 4; ++s) {
            float uv = pre[s];
            // distance-4 prefetch; wrap stays inside the chunk (values unused)
            pre[s] = u[idx + (unsigned)((((j + 4 + s) & (Lc - 1))) * H_)];
#pragma unroll
            for (int n = 0; n < NQ_; ++n) {
                float tr = fmaf(wr[n], sr[n], fmaf(-wi[n], si[n], uv));
                float ti = fmaf(wr[n], si[n], wi[n] * sr[n]);
                sr[n] = tr; si[n] = ti;
            }
        }
    }
    float2* sp = states + ((size_t)bc * N_ + nb) * H_ + h;
#pragma unroll
    for (int n = 0; n < NQ_; ++n) sp[(size_t)n * H_] = make_float2(sr[n], si[n]);
}

// ---------------- kernel C: cross-chunk scan (in place: local-end -> entry) --------
template <int C_>
__global__ __launch_bounds__(256) void chunk_scan(const float2* __restrict__ wLc,
                                                  float2* __restrict__ states) {
    int t = blockIdx.x * blockDim.x + threadIdx.x;
    int h = t % H_;
    int bn = t / H_;
    int n = bn % N_;
    int b = bn / N_;
    float2 wl = wLc[n * H_ + h];
    float er = 0.0f, ei = 0.0f;
    float2* p0 = states + ((size_t)(b * C_) * N_ + n) * H_ + h;
    const size_t stride = (size_t)N_ * H_;
    float2 nxt = *p0;
#pragma unroll
    for (int c = 0; c < C_; ++c) {
        float2 le = nxt;
        float2* p = p0 + (size_t)c * stride;
        if (c + 1 < C_) nxt = p[stride];  // prefetch next before FMA/store
        *p = make_float2(er, ei);
        float nr2 = fmaf(wl.x, er, fmaf(-wl.y, ei, le.x));
        float ni2 = fmaf(wl.x, ei, fmaf(wl.y, er, le.y));
        er = nr2; ei = ni2;
    }
}

// ---------------- kernel D: re-scan with entry state, emit gelu(y) ----------------
// 2 lanes per h (16 modes each). Paired-j: per 2 timesteps, half 0 emits gelu/store
// for j, half 1 for j+1 -> erf runs unmasked, stores are full-wave.
template <int C_>
__global__ __launch_bounds__(256, 4) void scan_out(const float* __restrict__ u,
                                                   const float4* __restrict__ modes,
                                                   const float2* __restrict__ states,
                                                   const float* __restrict__ Dscal,
                                                   float* __restrict__ y) {
    constexpr int Lc = L_ / C_;
    int t = blockIdx.x * blockDim.x + threadIdx.x;
    int lane = t & 63;
    int w = t >> 6;
    int half = lane >> 5;
    int k = lane & 31;
    int h = (w & 31) * 32 + k;
    int bc = w >> 5;
    int c = bc % C_;
    int b = bc / C_;
    int nb = half * NH_;
    float Dv = Dscal[0];
    float wr[NH_], wi[NH_], gr[NH_], gi[NH_], sr[NH_], si[NH_];
#pragma unroll
    for (int n = 0; n < NH_; ++n) {
        float4 m = modes[(nb + n) * H_ + h];
        wr[n] = m.x; wi[n] = m.y; gr[n] = m.z; gi[n] = m.w;
        float2 e = states[((size_t)bc * N_ + nb + n) * H_ + h];
        sr[n] = e.x; si[n] = e.y;
    }
    unsigned idx = ((unsigned)b * L_ + (unsigned)c * Lc) * H_ + (unsigned)h;
    unsigned idy = idx + (unsigned)(half * H_);
    float pre0 = u[idx];
    float pre1 = u[idx + (unsigned)H_];
    for (int j = 0; j < Lc; j += 2) {
        float uvA = pre0, uvB = pre1;
        pre0 = u[idx + (unsigned)(((j + 2) & (Lc - 1)) * H_)];
        pre1 = u[idx + (unsigned)(((j + 3) & (Lc - 1)) * H_)];
        float accA = 0.0f, accB = 0.0f;
#pragma unroll
        for (int n = 0; n < NH_; ++n) {
            float tr = fmaf(wr[n], sr[n], fmaf(-wi[n], si[n], uvA));
            float ti = fmaf(wr[n], si[n], wi[n] * sr[n]);
            accA = fmaf(gr[n], tr, fmaf(gi[n], ti, accA));
            float tr2 = fmaf(wr[n], tr, fmaf(-wi[n], ti, uvB));
            float ti2 = fmaf(wr[n], ti, wi[n] * tr);
            sr[n] = tr2; si[n] = ti2;
            accB = fmaf(gr[n], tr2, fmaf(gi[n], ti2, accB));
        }
        accA += __shfl_xor(accA, 32, 64);
        accB += __shfl_xor(accB, 32, 64);
        float uvS = half ? uvB : uvA;
        float accS = half ? accB : accA;
        float v = fmaf(Dv, uvS, accS);
        float g = 0.5f * v * (1.0f + erff(v * 0.70710678118654752f));
        y[idy + (unsigned)(j * H_)] = g;
    }
}

// ---------------- launcher ----------------
template <int C_>
static void launch_all(const float* u, const float* log_dt, const float* A_real,
                       const float* A_imag, const float* C_real, const float* C_imag,
                       const float* Dscal, float* y, char* ws, hipStream_t stream) {
    float4* modes = (float4*)ws;                        // H*N*16 = 512 KiB
    float2* wLc   = (float2*)(ws + 524288);             // H*N*8  = 256 KiB
    float2* states = (float2*)(ws + 786432);            // B*C*N*H*8
    int log2Lc = 0;
    for (int v = L_ / C_; v > 1; v >>= 1) ++log2Lc;

    constexpr int nwaves_local = B_ * C_ * (H_ / 16);   // 4 lanes per h
    constexpr int nblocks_local = nwaves_local / 4;
    constexpr int nwaves_out = B_ * C_ * (H_ / 32);     // 2 lanes per h
    constexpr int nblocks_out = nwaves_out / 4;

    modes_kernel<<<(H_ * N_) / 256, 256, 0, stream>>>(log_dt, A_real, A_imag,
                                                      C_real, C_imag, modes, wLc, log2Lc);
    scan_local<C_><<<nblocks_local, 256, 0, stream>>>(u, modes, states);
    chunk_scan<C_><<<(B_ * N_ * H_) / 256, 256, 0, stream>>>(wLc, states);
    scan_out<C_><<<nblocks_out, 256, 0, stream>>>(u, modes, states, Dscal, y);
}

extern "C" void kernel_launch(void* const* d_in, const int* in_sizes, int n_in,
                              void* d_out, int out_size, void* d_ws, size_t ws_size,
                              hipStream_t stream) {
    const float* u      = (const float*)d_in[0];
    const float* log_dt = (const float*)d_in[1];
    const float* A_real = (const float*)d_in[2];
    const float* A_imag = (const float*)d_in[3];
    const float* C_real = (const float*)d_in[4];
    const float* C_imag = (const float*)d_in[5];
    const float* Dscal  = (const float*)d_in[6];
    float* y = (float*)d_out;
    char* ws = (char*)d_ws;

    const size_t base = 786432;
    auto need = [&](int C) { return base + (size_t)B_ * C * N_ * H_ * 8; };
    if (ws_size >= need(32)) {
        launch_all<32>(u, log_dt, A_real, A_imag, C_real, C_imag, Dscal, y, ws, stream);
    } else if (ws_size >= need(16)) {
        launch_all<16>(u, log_dt, A_real, A_imag, C_real, C_imag, Dscal, y, ws, stream);
    } else {
        launch_all<8>(u, log_dt, A_real, A_imag, C_real, C_imag, Dscal, y, ws, stream);
    }
}